// Round 4
// baseline (1119.963 us; speedup 1.0000x reference)
//
#include <hip/hip_runtime.h>
#include <hip/hip_bf16.h>
#include <cmath>

#define D_    1024
#define B_    128
#define N_    576
#define ROWS_ (B_*N_)
#define TWOD_ 2048
#define TAU_  1e-5f
#define NU_   8

__device__ __forceinline__ float waveReduceSum(float v){
  #pragma unroll
  for (int m=32;m;m>>=1) v += __shfl_xor(v,m,64);
  return v;
}
__device__ __forceinline__ float waveReduceMax(float v){
  #pragma unroll
  for (int m=32;m;m>>=1) v = fmaxf(v,__shfl_xor(v,m,64));
  return v;
}

// Fused init: blocks 0..127 compute temb; blocks 128+ grid-stride fill
// bias-initialized GEMM outputs and zeroed accumulators.
// Fill layout (cumulative float offsets within the fill space):
//   h1[131072]=bt1, cond[131072]=bt2, qv=0, kq=0, wv=0, newemb=bp,
//   rbuf[262144]=bd1, wimg=0, pcorr=0, sdelta=0
__global__ __launch_bounds__(256) void k_init0(const int* __restrict__ ts,
    float* __restrict__ temb, float* __restrict__ h1, float* __restrict__ cond,
    float* __restrict__ qv, float* __restrict__ kq, float* __restrict__ wv,
    float* __restrict__ newemb, float* __restrict__ rbuf, float* __restrict__ wimg,
    float* __restrict__ pcorr, float* __restrict__ sdelta, int* __restrict__ cnt,
    const float* __restrict__ bt1, const float* __restrict__ bt2,
    const float* __restrict__ bp, const float* __restrict__ bd1){
  int bid = blockIdx.x;
  if (bid < 128){
    float t = (float)ts[bid];
    for (int i=threadIdx.x; i<512; i+=256){
      float dv = expf((float)(2*i) * (-9.210340371976184f/1024.f));
      float a = t*dv;
      temb[bid*D_ + 2*i]   = sinf(a);
      temb[bid*D_ + 2*i+1] = cosf(a);
    }
    return;
  }
  int idx0 = (bid-128)*256 + threadIdx.x;
  int stride = (gridDim.x-128)*256;
  if (idx0 == 0) *cnt = 0;
  for (int j=idx0; j<1327104; j+=stride){
    if      (j <  131072) h1[j]            = bt1[j&1023];
    else if (j <  262144) cond[j-131072]   = bt2[j&1023];
    else if (j <  393216) qv[j-262144]     = 0.f;
    else if (j <  524288) kq[j-393216]     = 0.f;
    else if (j <  655360) wv[j-524288]     = 0.f;
    else if (j <  786432) newemb[j-655360] = bp[j&1023];
    else if (j < 1048576) rbuf[j-786432]   = bd1[(j-786432)&2047];
    else if (j < 1179648) wimg[j-1048576]  = 0.f;
    else if (j < 1253376) pcorr[j-1179648] = 0.f;
    else                  sdelta[j-1253376]= 0.f;
  }
}

// K-split atomic GEMM: C[128,nout] += Astage[128,1024] @ W over k-chunk.
// grid (nout/256, 32, 4), block 256. Block: 4 rows (by*4), 256 cols, k-chunk bz*256.
// mode: 0 plain A; 1 silu(A); 2 A+A2. tmode: 0 W[k*ldw+col]; 1 W[col*ldw+k].
// C must be pre-initialized with the bias (k_init0).
__global__ __launch_bounds__(256) void k_gemm2(const float* __restrict__ A,
    const float* __restrict__ A2, const float* __restrict__ W, int ldw,
    float* __restrict__ C, int nout, int mode, int tmode){
  __shared__ float a[4][256];
  int r0 = blockIdx.y*4;
  int kbase = blockIdx.z*256;
  #pragma unroll
  for (int r=0;r<4;r++){
    float v = A[(size_t)(r0+r)*D_ + kbase + threadIdx.x];
    if (mode==1) v = v/(1.f+expf(-v));
    else if (mode==2) v += A2[(size_t)(r0+r)*D_ + kbase + threadIdx.x];
    a[r][threadIdx.x] = v;
  }
  __syncthreads();
  int col = blockIdx.x*256 + threadIdx.x;
  float acc0=0.f, acc1=0.f, acc2=0.f, acc3=0.f;
  if (tmode==0){
    const float* wp = W + (size_t)kbase*ldw + col;
    #pragma unroll 8
    for (int k=0;k<256;k++){
      float wv = wp[(size_t)k*ldw];
      acc0=fmaf(a[0][k],wv,acc0); acc1=fmaf(a[1][k],wv,acc1);
      acc2=fmaf(a[2][k],wv,acc2); acc3=fmaf(a[3][k],wv,acc3);
    }
  } else {
    const float* wp = W + (size_t)col*ldw + kbase;
    #pragma unroll 8
    for (int k=0;k<256;k++){
      float wv = wp[k];
      acc0=fmaf(a[0][k],wv,acc0); acc1=fmaf(a[1][k],wv,acc1);
      acc2=fmaf(a[2][k],wv,acc2); acc3=fmaf(a[3][k],wv,acc3);
    }
  }
  atomicAdd(&C[(size_t)(r0  )*nout+col], acc0);
  atomicAdd(&C[(size_t)(r0+1)*nout+col], acc1);
  atomicAdd(&C[(size_t)(r0+2)*nout+col], acc2);
  atomicAdd(&C[(size_t)(r0+3)*nout+col], acc3);
}

// s[row] = text[b] . imgf[row]   (one wave per row)
__global__ __launch_bounds__(256) void k_dots(const float* __restrict__ text,
    const float* __restrict__ imgf, float* __restrict__ s){
  int wave = threadIdx.x>>6, lane = threadIdx.x&63;
  int row = blockIdx.x*4 + wave;
  int b = row / N_;
  const float4* ip = (const float4*)(imgf + (size_t)row*D_);
  const float4* tp = (const float4*)(text + (size_t)b*D_);
  float acc=0.f;
  #pragma unroll
  for (int p=0;p<4;p++){
    float4 a = ip[p*64+lane];
    float4 t = tp[p*64+lane];
    acc = fmaf(a.x,t.x,acc); acc = fmaf(a.y,t.y,acc);
    acc = fmaf(a.z,t.z,acc); acc = fmaf(a.w,t.w,acc);
  }
  acc = waveReduceSum(acc);
  if (lane==0) s[row]=acc;
}

// softmax over N_ of s[b,:]; append entries with w>TAU to list (no dense store)
__global__ __launch_bounds__(256) void k_softmax1(const float* __restrict__ s,
    int* count, int* lrow, float* liw){
  int b = blockIdx.x;
  __shared__ float rbuf[4];
  const float* sp = s + b*N_;
  float m = -3e38f;
  for (int i=threadIdx.x;i<N_;i+=256) m = fmaxf(m, sp[i]);
  m = waveReduceMax(m);
  if ((threadIdx.x&63)==0) rbuf[threadIdx.x>>6]=m;
  __syncthreads();
  m = fmaxf(fmaxf(rbuf[0],rbuf[1]),fmaxf(rbuf[2],rbuf[3]));
  __syncthreads();
  float sum=0.f;
  for (int i=threadIdx.x;i<N_;i+=256) sum += expf(sp[i]-m);
  sum = waveReduceSum(sum);
  if ((threadIdx.x&63)==0) rbuf[threadIdx.x>>6]=sum;
  __syncthreads();
  sum = rbuf[0]+rbuf[1]+rbuf[2]+rbuf[3];
  float inv = 1.f/sum;
  for (int i=threadIdx.x;i<N_;i+=256){
    float wi = expf(sp[i]-m)*inv;
    if (wi > TAU_){
      int pos = atomicAdd(count,1);
      if (pos < ROWS_){ lrow[pos]=b*N_+i; liw[pos]=wi; }
    }
  }
}

// listed rows: sdelta[row] = iw * (imgf[row] . kq[b])
__global__ __launch_bounds__(256) void k_lsparse(const float* __restrict__ imgf,
    const float* __restrict__ kq, const int* __restrict__ count, const int* __restrict__ lrow,
    const float* __restrict__ liw, float* __restrict__ sdelta){
  int wave=threadIdx.x>>6, lane=threadIdx.x&63;
  int cnt = min(*count, ROWS_);
  for (int e = blockIdx.x*4+wave; e<cnt; e += gridDim.x*4){
    int row=lrow[e], b=row/N_; float iw=liw[e];
    const float4* ip=(const float4*)(imgf+(size_t)row*D_);
    const float4* kp=(const float4*)(kq + b*D_);
    float acc=0.f;
    #pragma unroll
    for (int p=0;p<4;p++){
      int c = p*64+lane;
      float4 a = ip[c];
      float4 k = kp[c];
      acc = fmaf(a.x,k.x,acc); acc = fmaf(a.y,k.y,acc);
      acc = fmaf(a.z,k.z,acc); acc = fmaf(a.w,k.w,acc);
    }
    acc = waveReduceSum(acc);
    if (lane==0) sdelta[row] = iw*acc;
  }
}

// wgt = softmax over N_ of (x + sdelta)
__global__ __launch_bounds__(256) void k_softmax2(const float* __restrict__ x,
    const float* __restrict__ sdelta, float* __restrict__ w){
  int b = blockIdx.x;
  __shared__ float rbuf[4];
  const float* xp = x + b*N_;
  const float* dp = sdelta + b*N_;
  float m = -3e38f;
  for (int i=threadIdx.x;i<N_;i+=256) m = fmaxf(m, xp[i]+dp[i]);
  m = waveReduceMax(m);
  if ((threadIdx.x&63)==0) rbuf[threadIdx.x>>6]=m;
  __syncthreads();
  m = fmaxf(fmaxf(rbuf[0],rbuf[1]),fmaxf(rbuf[2],rbuf[3]));
  __syncthreads();
  float sum=0.f;
  for (int i=threadIdx.x;i<N_;i+=256) sum += expf(xp[i]+dp[i]-m);
  sum = waveReduceSum(sum);
  if ((threadIdx.x&63)==0) rbuf[threadIdx.x>>6]=sum;
  __syncthreads();
  sum = rbuf[0]+rbuf[1]+rbuf[2]+rbuf[3];
  float inv = 1.f/sum;
  float* wp = w + b*N_;
  for (int i=threadIdx.x;i<N_;i+=256)
    wp[i] = expf(xp[i]+dp[i]-m)*inv;
}

// wimg[b,:] += (weight[row]*iw) * imgf[row,:] over listed rows
__global__ __launch_bounds__(256) void k_wimg(const float* __restrict__ imgf,
    const float* __restrict__ wgt, const int* __restrict__ count, const int* __restrict__ lrow,
    const float* __restrict__ liw, float* __restrict__ wimg){
  int cnt = min(*count, ROWS_);
  for (int e = blockIdx.x; e<cnt; e += gridDim.x){
    int row=lrow[e], b=row/N_;
    float coef = liw[e]*wgt[row];
    const float* src = imgf + (size_t)row*D_;
    for (int i=threadIdx.x;i<D_;i+=256)
      atomicAdd(&wimg[b*D_+i], coef*src[i]);
  }
}

// p0[b] = sum_j relu(r[b,j])*wd2[j] + bd2
__global__ __launch_bounds__(256) void k_p0(const float* __restrict__ r,
    const float* __restrict__ wd2, const float* __restrict__ bd2, float* __restrict__ p0){
  __shared__ float rbuf[4];
  int b=blockIdx.x;
  float acc=0.f;
  for (int j=threadIdx.x;j<TWOD_;j+=256)
    acc = fmaf(fmaxf(r[b*TWOD_+j],0.f), wd2[j], acc);
  acc = waveReduceSum(acc);
  if((threadIdx.x&63)==0) rbuf[threadIdx.x>>6]=acc;
  __syncthreads();
  if (threadIdx.x==0) p0[b] = rbuf[0]+rbuf[1]+rbuf[2]+rbuf[3] + bd2[0];
}

// exact correction for listed rows:
// p_corr[row] += sum_j (relu(r[b,j]+iw*G_j) - relu(r[b,j]))*wd2[j],  G = imgf[row]@Wd1_bot
__global__ __launch_bounds__(256) void k_corr(const float* __restrict__ imgf,
    const float* __restrict__ Wd1, const float* __restrict__ r, const float* __restrict__ wd2,
    const int* __restrict__ count, const int* __restrict__ lrow, const float* __restrict__ liw,
    float* __restrict__ p_corr){
  __shared__ __align__(16) float img[D_][NU_];
  __shared__ float rbuf[4];
  int j = blockIdx.x*256 + threadIdx.x;
  float wd2j = wd2[j];
  int cnt = min(*count, ROWS_);
  int NG = gridDim.y;
  for (int base = blockIdx.y*NU_; base < cnt; base += NG*NU_){
    int nu = min(NU_, cnt-base);
    __syncthreads();
    for (int u=0;u<nu;u++){
      const float* src = imgf + (size_t)lrow[base+u]*D_;
      for (int i=threadIdx.x;i<D_;i+=256) img[i][u]=src[i];
    }
    for (int u=nu;u<NU_;u++)
      for (int i=threadIdx.x;i<D_;i+=256) img[i][u]=0.f;
    __syncthreads();
    float g[NU_];
    #pragma unroll
    for (int u=0;u<NU_;u++) g[u]=0.f;
    const float* wp = Wd1 + (size_t)D_*TWOD_ + j;
    #pragma unroll 8
    for (int e=0;e<D_;e++){
      float wv = wp[(size_t)e*TWOD_];
      const float4* ir = (const float4*)(&img[e][0]);
      float4 i0 = ir[0], i1 = ir[1];
      g[0]=fmaf(i0.x,wv,g[0]); g[1]=fmaf(i0.y,wv,g[1]);
      g[2]=fmaf(i0.z,wv,g[2]); g[3]=fmaf(i0.w,wv,g[3]);
      g[4]=fmaf(i1.x,wv,g[4]); g[5]=fmaf(i1.y,wv,g[5]);
      g[6]=fmaf(i1.z,wv,g[6]); g[7]=fmaf(i1.w,wv,g[7]);
    }
    for (int u=0;u<nu;u++){
      int row = lrow[base+u];
      float rv = r[(size_t)(row/N_)*TWOD_ + j];
      float c  = rv + liw[base+u]*g[u];
      float contrib = (fmaxf(c,0.f)-fmaxf(rv,0.f))*wd2j;
      contrib = waveReduceSum(contrib);
      if ((threadIdx.x&63)==0) rbuf[threadIdx.x>>6]=contrib;
      __syncthreads();
      if (threadIdx.x==0) atomicAdd(&p_corr[row], rbuf[0]+rbuf[1]+rbuf[2]+rbuf[3]);
      __syncthreads();
    }
  }
}

__global__ __launch_bounds__(256) void k_final(const float* __restrict__ p0,
    const float* __restrict__ p_corr, const float* __restrict__ wgt, float* __restrict__ out){
  int i = blockIdx.x*256+threadIdx.x;
  if (i<ROWS_){
    int b = i/N_;
    out[i] = p0[b] + p_corr[i] + wgt[i];
  }
}

extern "C" void kernel_launch(void* const* d_in, const int* in_sizes, int n_in,
                              void* d_out, int out_size, void* d_ws, size_t ws_size,
                              hipStream_t stream) {
  const float* x    = (const float*)d_in[0];
  const int*   ts   = (const int*)  d_in[1];
  const float* text = (const float*)d_in[2];
  const float* imgf = (const float*)d_in[3];
  const float* Wq   = (const float*)d_in[4];
  const float* Wk   = (const float*)d_in[5];
  const float* Wv   = (const float*)d_in[6];
  const float* Wp   = (const float*)d_in[7];
  const float* bp   = (const float*)d_in[8];
  const float* Wt1  = (const float*)d_in[9];
  const float* bt1  = (const float*)d_in[10];
  const float* Wt2  = (const float*)d_in[11];
  const float* bt2  = (const float*)d_in[12];
  const float* Wd1  = (const float*)d_in[13];
  const float* bd1  = (const float*)d_in[14];
  const float* Wd2  = (const float*)d_in[15];
  const float* bd2  = (const float*)d_in[16];
  float* out = (float*)d_out;

  float* f = (float*)d_ws;
  float* temb   = f;            // 131072
  float* h1     = f +  131072;  // 131072
  float* cond   = f +  262144;  // 131072
  float* qv     = f +  393216;  // 131072
  float* kq     = f +  524288;  // 131072
  float* wv     = f +  655360;  // 131072
  float* newemb = f +  786432;  // 131072
  float* rbuf   = f +  917504;  // 262144
  float* wimg   = f + 1179648;  // 131072
  float* sbuf   = f + 1310720;  // 73728
  float* wgt    = f + 1384448;  // 73728
  float* pcorr  = f + 1458176;  // 73728
  float* sdelta = f + 1531904;  // 73728
  float* liw    = f + 1605632;  // 73728
  int*   lrow   = (int*)(f + 1679360); // 73728
  float* p0     = f + 1753088;  // 128
  int*   cnt    = (int*)(f + 1753216);

  // fused init (temb + all bias/zero fills)
  k_init0<<<1152,256,0,stream>>>(ts, temb, h1, cond, qv, kq, wv, newemb, rbuf,
                                 wimg, pcorr, sdelta, cnt, bt1, bt2, bp, bd1);
  // conditioning chain: h1 = temb@Wt1+bt1 ; cond = silu(h1)@Wt2+bt2
  k_gemm2<<<dim3(4,32,4),256,0,stream>>>(temb, nullptr, Wt1, D_, h1,   D_, 0, 0);
  k_gemm2<<<dim3(4,32,4),256,0,stream>>>(h1,   nullptr, Wt2, D_, cond, D_, 1, 0);
  // i_w logits (full image pass) + softmax/list build
  k_dots<<<ROWS_/4,256,0,stream>>>(text, imgf, sbuf);
  k_softmax1<<<B_,256,0,stream>>>(sbuf, cnt, lrow, liw);
  // qv = (text+cond)@Wq ; kq = qv@Wk^T
  k_gemm2<<<dim3(4,32,4),256,0,stream>>>(text, cond, Wq, D_, qv, D_, 2, 0);
  k_gemm2<<<dim3(4,32,4),256,0,stream>>>(qv, nullptr, Wk, D_, kq, D_, 0, 1);
  // attention: sparse logit deltas, softmax -> weight
  k_lsparse<<<64,256,0,stream>>>(imgf, kq, cnt, lrow, liw, sdelta);
  k_softmax2<<<B_,256,0,stream>>>(x, sdelta, wgt);
  // weighted image sum (sparse) + new_emb chain
  k_wimg<<<128,256,0,stream>>>(imgf, wgt, cnt, lrow, liw, wimg);
  k_gemm2<<<dim3(4,32,4),256,0,stream>>>(wimg, cond, Wv, D_, wv, D_, 2, 0);
  k_gemm2<<<dim3(4,32,4),256,0,stream>>>(wv, nullptr, Wp, D_, newemb, D_, 0, 0);
  // r = new_emb @ Wd1_top + bd1
  k_gemm2<<<dim3(8,32,4),256,0,stream>>>(newemb, nullptr, Wd1, TWOD_, rbuf, TWOD_, 0, 0);
  // decoder baseline + exact sparse correction
  k_p0<<<B_,256,0,stream>>>(rbuf, Wd2, bd2, p0);
  k_corr<<<dim3(8,64),256,0,stream>>>(imgf, Wd1, rbuf, Wd2, cnt, lrow, liw, pcorr);
  // out = p0 + corr + weight
  k_final<<<(ROWS_+255)/256,256,0,stream>>>(p0, pcorr, wgt, out);
}